// Round 1
// baseline (1254.130 us; speedup 1.0000x reference)
//
#include <hip/hip_runtime.h>
#include <hip/hip_cooperative_groups.h>

#define HDIM 4096
#define NROWS 16384      // B*S = 4*4096
#define TPB 256
#define GRID 1024        // 4 blocks/CU * 256 CU -> co-resident for cooperative launch
#define RPB (NROWS / GRID)   // 16 rows per block
#define EPS_RMS 1e-6f

namespace cg = cooperative_groups;

typedef float f32x4 __attribute__((ext_vector_type(4)));

__device__ __forceinline__ float wave_reduce_sum(float v) {
    #pragma unroll
    for (int off = 32; off > 0; off >>= 1)
        v += __shfl_down(v, off, 64);
    return v;
}
__device__ __forceinline__ float wave_reduce_max(float v) {
    #pragma unroll
    for (int off = 32; off > 0; off >>= 1)
        v = fmaxf(v, __shfl_down(v, off, 64));
    return v;
}

// Fused: phase 1 computes x = x1+x2 (store, temporal: we want it in LLC),
// per-row inv_rms (kept in LDS), block-level abs-max -> 1 atomicMax/block.
// grid.sync(). Phase 2 re-reads x (mostly LLC-resident: x1/x2 were read
// non-temporally and y1/y2 are written non-temporally, so x is the only
// temporal stream), quantizes, writes y1/y2.
__global__ __launch_bounds__(TPB, 4) void fused_kernel(
    const f32x4* __restrict__ x1, const f32x4* __restrict__ x2,
    const f32x4* __restrict__ gamma, f32x4* __restrict__ xout,
    f32x4* __restrict__ y1, f32x4* __restrict__ y2,
    float* __restrict__ scales, unsigned int* __restrict__ gmax)
{
    const int t    = threadIdx.x;
    const int wave = t >> 6, lane = t & 63;
    __shared__ float red_s[2][4], red_m[2][4];   // parity double-buffer
    __shared__ float inv_s[RPB];

    // gamma: each thread uses the same 4 float4 for every row -> load once.
    f32x4 g[4];
    #pragma unroll
    for (int k = 0; k < 4; ++k) g[k] = gamma[t + k * TPB];

    float blkmax = 0.f;   // meaningful on thread 0 only

    // ---------------- phase 1: residual add + stats ----------------
    #pragma unroll 1
    for (int r = 0; r < RPB; ++r) {
        const int row = blockIdx.x * RPB + r;
        const size_t rowbase = (size_t)row * (HDIM / 4);
        float ss = 0.f, gm = 0.f;
        #pragma unroll
        for (int k = 0; k < 4; ++k) {
            const int idx = t + k * TPB;
            f32x4 a = __builtin_nontemporal_load(&x1[rowbase + idx]);
            f32x4 b = __builtin_nontemporal_load(&x2[rowbase + idx]);
            f32x4 v = a + b;
            xout[rowbase + idx] = v;          // temporal: re-read in phase 2
            ss += v.x * v.x + v.y * v.y + v.z * v.z + v.w * v.w;
            f32x4 ag = v * g[k];
            gm = fmaxf(gm, fmaxf(fmaxf(fabsf(ag.x), fabsf(ag.y)),
                                 fmaxf(fabsf(ag.z), fabsf(ag.w))));
        }
        float wsum = wave_reduce_sum(ss);
        float wmax = wave_reduce_max(gm);
        if (lane == 0) { red_s[r & 1][wave] = wsum; red_m[r & 1][wave] = wmax; }
        __syncthreads();
        if (t == 0) {
            float tot = (red_s[r & 1][0] + red_s[r & 1][1])
                      + (red_s[r & 1][2] + red_s[r & 1][3]);
            float inv = rsqrtf(tot * (1.0f / HDIM) + EPS_RMS);
            inv_s[r] = inv;
            float m = fmaxf(fmaxf(red_m[r & 1][0], red_m[r & 1][1]),
                            fmaxf(red_m[r & 1][2], red_m[r & 1][3])) * inv;
            blkmax = fmaxf(blkmax, m);
        }
        // no second barrier needed: next iteration writes the other parity,
        // and writes to this parity only happen after the NEXT barrier.
    }
    if (t == 0) atomicMax(gmax, __float_as_uint(blkmax));  // floats >=0 order as uints

    // ---------------- grid-wide barrier ----------------
    cg::this_grid().sync();

    const unsigned int mu =
        __hip_atomic_load(gmax, __ATOMIC_RELAXED, __HIP_MEMORY_SCOPE_AGENT);
    const float maxv = __uint_as_float(mu);
    const float qs   = 127.0f / maxv;
    if (blockIdx.x == 0 && t == 0) {
        float s = maxv * (1.0f / 127.0f);
        scales[0] = s;
        scales[1] = s;
    }

    // ---------------- phase 2: quantize ----------------
    // Reverse row order: most-recently-written rows first (L2/LLC recency).
    #pragma unroll 1
    for (int r = RPB - 1; r >= 0; --r) {
        const int row = blockIdx.x * RPB + r;
        const size_t rowbase = (size_t)row * (HDIM / 4);
        const float c = inv_s[r] * qs;    // fold per-row inv_rms into quant factor
        #pragma unroll
        for (int k = 0; k < 4; ++k) {
            const int idx = t + k * TPB;
            f32x4 v = __builtin_nontemporal_load(&xout[rowbase + idx]);
            f32x4 q;
            q.x = fminf(fmaxf(rintf(v.x * g[k].x * c), -128.f), 127.f);
            q.y = fminf(fmaxf(rintf(v.y * g[k].y * c), -128.f), 127.f);
            q.z = fminf(fmaxf(rintf(v.z * g[k].z * c), -128.f), 127.f);
            q.w = fminf(fmaxf(rintf(v.w * g[k].w * c), -128.f), 127.f);
            __builtin_nontemporal_store(q, &y1[rowbase + idx]);
            __builtin_nontemporal_store(q, &y2[rowbase + idx]);
        }
    }
}

extern "C" void kernel_launch(void* const* d_in, const int* in_sizes, int n_in,
                              void* d_out, int out_size, void* d_ws, size_t ws_size,
                              hipStream_t stream) {
    (void)in_sizes; (void)n_in; (void)out_size; (void)ws_size;
    const f32x4* x1    = (const f32x4*)d_in[0];
    const f32x4* x2    = (const f32x4*)d_in[1];
    const f32x4* gamma = (const f32x4*)d_in[2];
    // d_in[3], d_in[4] (smooth_scale1/2) are unused by the reference computation.

    const size_t N = (size_t)NROWS * HDIM;  // 67,108,864
    float* out   = (float*)d_out;
    f32x4* y1    = (f32x4*)out;             // [0, N)
    f32x4* y2    = (f32x4*)(out + N);       // [N, 2N)
    f32x4* xo    = (f32x4*)(out + 2 * N);   // [2N, 3N)
    float* scales = out + 3 * N;            // scale1, scale2

    unsigned int* gmax = (unsigned int*)d_ws;

    hipMemsetAsync(d_ws, 0, 16, stream);    // zero the abs-max slot

    void* args[8] = { (void*)&x1, (void*)&x2, (void*)&gamma, (void*)&xo,
                      (void*)&y1, (void*)&y2, (void*)&scales, (void*)&gmax };
    hipLaunchCooperativeKernel((const void*)fused_kernel,
                               dim3(GRID), dim3(TPB), args, 0u, stream);
}

// Round 2
// 1169.171 us; speedup vs baseline: 1.0727x; 1.0727x over previous
//
#include <hip/hip_runtime.h>

#define HDIM 4096
#define NROWS 16384      // B*S = 4*4096
#define TPB 256
#define EPS_RMS 1e-6f

typedef float f32x4 __attribute__((ext_vector_type(4)));

__device__ __forceinline__ float wave_reduce_sum(float v) {
    #pragma unroll
    for (int off = 32; off > 0; off >>= 1)
        v += __shfl_down(v, off, 64);
    return v;
}
__device__ __forceinline__ float wave_reduce_max(float v) {
    #pragma unroll
    for (int off = 32; off > 0; off >>= 1)
        v = fmaxf(v, __shfl_down(v, off, 64));
    return v;
}

// Pass 1: x = x1 + x2 (temporal store -> LLC; re-read in pass 2), per-row
// inv_rms (ws), global abs-max of normalized output via atomicMax on uint
// bits (valid: all values >= 0). x1/x2 are read with the non-temporal hint:
// they are dead after this pass and must not evict x from L2/LLC.
__global__ __launch_bounds__(TPB) void pass1_kernel(
    const f32x4* __restrict__ x1, const f32x4* __restrict__ x2,
    const f32x4* __restrict__ gamma, f32x4* __restrict__ xout,
    float* __restrict__ inv_rms, unsigned int* __restrict__ gmax) {
    const int row = blockIdx.x;
    const int t   = threadIdx.x;
    const size_t rowbase = (size_t)row * (HDIM / 4);

    float ss = 0.f;   // sum of squares of x
    float gm = 0.f;   // max |x * gamma| (inv_rms applied after reduce)
    #pragma unroll
    for (int k = 0; k < 4; ++k) {
        const int idx = t + k * TPB;
        f32x4 a = __builtin_nontemporal_load(&x1[rowbase + idx]);
        f32x4 b = __builtin_nontemporal_load(&x2[rowbase + idx]);
        f32x4 v = a + b;
        xout[rowbase + idx] = v;          // temporal: pass 2 re-reads this
        ss += v.x * v.x + v.y * v.y + v.z * v.z + v.w * v.w;
        f32x4 g = gamma[idx];
        f32x4 ag = v * g;
        gm = fmaxf(gm, fmaxf(fmaxf(fabsf(ag.x), fabsf(ag.y)),
                             fmaxf(fabsf(ag.z), fabsf(ag.w))));
    }

    __shared__ float red_s[4];
    __shared__ float red_m[4];
    const int wave = t >> 6, lane = t & 63;
    float wsum = wave_reduce_sum(ss);
    float wmax = wave_reduce_max(gm);
    if (lane == 0) { red_s[wave] = wsum; red_m[wave] = wmax; }
    __syncthreads();
    if (t == 0) {
        float tot = (red_s[0] + red_s[1]) + (red_s[2] + red_s[3]);
        float inv = rsqrtf(tot * (1.0f / HDIM) + EPS_RMS);
        inv_rms[row] = inv;
        float m = fmaxf(fmaxf(red_m[0], red_m[1]), fmaxf(red_m[2], red_m[3])) * inv;
        atomicMax(gmax, __float_as_uint(m));  // device-scope; floats >=0 order as uints
    }
}

// Pass 2: recompute out = x * inv_rms * gamma, quantize with round-half-even,
// write y1, y2 (fp32 -- harness output dtype) and the two scale scalars.
// x is read with plain (temporal) loads -- it should largely hit L2/LLC.
// y1/y2 are written non-temporally: write-once data, keep it out of the
// caches so the remaining x lines survive.
__global__ __launch_bounds__(TPB) void pass2_kernel(
    const f32x4* __restrict__ x, const f32x4* __restrict__ gamma,
    const float* __restrict__ inv_rms, const unsigned int* __restrict__ gmax,
    f32x4* __restrict__ y1, f32x4* __restrict__ y2,
    float* __restrict__ scales) {
    const int row = blockIdx.x;
    const int t   = threadIdx.x;
    const float inv  = inv_rms[row];
    const float maxv = __uint_as_float(*gmax);
    const float qs   = 127.0f / maxv;     // multiply instead of divide by scale
    const float c    = inv * qs;          // fold per-row inv_rms into quant factor
    if (row == 0 && t == 0) {
        float scale = maxv * (1.0f / 127.0f);
        scales[0] = scale;
        scales[1] = scale;
    }
    const size_t rowbase = (size_t)row * (HDIM / 4);
    #pragma unroll
    for (int k = 0; k < 4; ++k) {
        const int idx = t + k * TPB;
        f32x4 v = x[rowbase + idx];
        f32x4 g = gamma[idx];
        f32x4 q;
        q.x = fminf(fmaxf(rintf(v.x * g.x * c), -128.f), 127.f);
        q.y = fminf(fmaxf(rintf(v.y * g.y * c), -128.f), 127.f);
        q.z = fminf(fmaxf(rintf(v.z * g.z * c), -128.f), 127.f);
        q.w = fminf(fmaxf(rintf(v.w * g.w * c), -128.f), 127.f);
        __builtin_nontemporal_store(q, &y1[rowbase + idx]);
        __builtin_nontemporal_store(q, &y2[rowbase + idx]);
    }
}

extern "C" void kernel_launch(void* const* d_in, const int* in_sizes, int n_in,
                              void* d_out, int out_size, void* d_ws, size_t ws_size,
                              hipStream_t stream) {
    (void)in_sizes; (void)n_in; (void)out_size; (void)ws_size;
    const float* x1    = (const float*)d_in[0];
    const float* x2    = (const float*)d_in[1];
    const float* gamma = (const float*)d_in[2];
    // d_in[3], d_in[4] (smooth_scale1/2) are unused by the reference computation.

    const size_t N = (size_t)NROWS * HDIM;  // 67,108,864
    float* out    = (float*)d_out;
    float* y1     = out;            // [0, N)
    float* y2     = out + N;        // [N, 2N)
    float* xo     = out + 2 * N;    // [2N, 3N)
    float* scales = out + 3 * N;    // scale1, scale2

    unsigned int* gmax = (unsigned int*)d_ws;
    float* inv_rms     = (float*)((char*)d_ws + 16);   // NROWS floats = 64 KiB

    hipMemsetAsync(d_ws, 0, 16, stream);  // zero the abs-max slot

    pass1_kernel<<<NROWS, TPB, 0, stream>>>(
        (const f32x4*)x1, (const f32x4*)x2, (const f32x4*)gamma,
        (f32x4*)xo, inv_rms, gmax);

    pass2_kernel<<<NROWS, TPB, 0, stream>>>(
        (const f32x4*)xo, (const f32x4*)gamma, inv_rms, gmax,
        (f32x4*)y1, (f32x4*)y2, scales);
}